// Round 7
// baseline (208.107 us; speedup 1.0000x reference)
//
#include <hip/hip_runtime.h>
#include <math.h>

#define N_NODES 100000
#define N_EDGES 1600000
#define F0 32
#define F1 16
#define F2 8
#define NCLS 6
#define NGRAPH 64

#define NB   196       // buckets of 512 nodes: ceil(100000/512)
#define BSH  9         // bucket shift (512 nodes/bucket, power of 2 -> exact)
#define GSZ  512       // nodes per bucket
#define NCH  256       // passA chunks
#define EPC  6250      // edges per chunk: N_EDGES / NCH exactly
#define PB   512       // passB / scan width
#define NBX  391       // xform blocks: ceil(N_NODES/256)
#define EPB  4093      // edges per xform block: ceil(N_EDGES/391)

// ---- fused: xw1 = x @ W1a (per node) + bucket histogram (per edge) ----
__global__ __launch_bounds__(256) void xform_k(
    const float* __restrict__ x, const float* __restrict__ W1a,
    float* __restrict__ xw1, const int* __restrict__ ei,
    int* __restrict__ bhist) {
    __shared__ float sW[F0 * F1];
    __shared__ int hist[256];
    int t = threadIdx.x, c = blockIdx.x;
    hist[t] = 0;
    for (int i = t; i < F0 * F1; i += 256) sW[i] = W1a[i];
    __syncthreads();

    // edge histogram for this block's chunk
    int base = c * EPB;
    for (int i = t; i < EPB; i += 256) {
        int idx = base + i;
        if (idx < N_EDGES) atomicAdd(&hist[ei[N_EDGES + idx] >> BSH], 1);
    }

    // node projection
    int n = c * 256 + t;
    if (n < N_NODES) {
        const float4* xp = reinterpret_cast<const float4*>(x) + n * (F0 / 4);
        float xi[F0];
#pragma unroll
        for (int q = 0; q < F0 / 4; q++) {
            float4 v = xp[q];
            xi[4 * q + 0] = v.x; xi[4 * q + 1] = v.y;
            xi[4 * q + 2] = v.z; xi[4 * q + 3] = v.w;
        }
        float o[F1];
#pragma unroll
        for (int j = 0; j < F1; j++) {
            float s = 0.0f;
#pragma unroll
            for (int k = 0; k < F0; k++) s += xi[k] * sW[k * F1 + j];
            o[j] = s;
        }
        float4* op = reinterpret_cast<float4*>(xw1) + n * (F1 / 4);
#pragma unroll
        for (int q = 0; q < F1 / 4; q++)
            op[q] = make_float4(o[4 * q + 0], o[4 * q + 1], o[4 * q + 2], o[4 * q + 3]);
    }
    __syncthreads();
    if (t < NB && hist[t]) atomicAdd(&bhist[t], hist[t]);
}

// ---- scan 196 bucket totals -> bbase (exclusive) and gcursor init ----
__global__ __launch_bounds__(256) void bscan_k(
    const int* __restrict__ bhist, int* __restrict__ bbase,
    int* __restrict__ gcursor) {
    __shared__ int sc[256];
    int t = threadIdx.x;
    int own = (t < NB) ? bhist[t] : 0;
    sc[t] = own;
    __syncthreads();
    for (int off = 1; off < 256; off <<= 1) {
        int v = sc[t];
        if (t >= off) v += sc[t - off];
        __syncthreads();
        sc[t] = v;
        __syncthreads();
    }
    bbase[t + 1] = sc[t];            // inclusive
    if (t == 0) bbase[0] = 0;
    gcursor[t] = sc[t] - own;        // exclusive start = append cursor
}

// ---- passA: partition edges into 196 dst-buckets; pack (dl<<17 | src) ----
__global__ __launch_bounds__(256) void passA_k(
    const int* __restrict__ ei, int* __restrict__ gcursor,
    int* __restrict__ pairs) {
    __shared__ int hist[256];
    __shared__ int cur[256];
    __shared__ int sdst[EPC];        // stage dst: read global once
    int t = threadIdx.x, c = blockIdx.x;
    hist[t] = 0;
    __syncthreads();
    int base = c * EPC;
    for (int i = t; i < EPC; i += 256) {
        int d = ei[N_EDGES + base + i];
        sdst[i] = d;
        atomicAdd(&hist[d >> BSH], 1);
    }
    __syncthreads();
    // reserve a contiguous sub-range of each bucket for this chunk
    cur[t] = hist[t] ? atomicAdd(&gcursor[t], hist[t]) : 0;
    __syncthreads();
    for (int i = t; i < EPC; i += 256) {
        int s = ei[base + i];
        int d = sdst[i];
        int b = d >> BSH;
        int dl = d & (GSZ - 1);
        int pos = atomicAdd(&cur[b], 1);          // LDS cursor
        pairs[pos] = (dl << 17) | s;
    }
}

// ---- passB: per-bucket counting sort by dl -> srcs (dst-sorted) + nodeptr ----
__global__ __launch_bounds__(PB) void passB_k(
    const int* __restrict__ pairs, const int* __restrict__ bbase,
    int* __restrict__ srcs, int* __restrict__ nodeptr) {
    __shared__ int hist[PB];
    __shared__ int buf[2][PB];
    __shared__ int cur[PB];
    int t = threadIdx.x, b = blockIdx.x;
    hist[t] = 0;
    __syncthreads();
    int e0 = bbase[b], e1 = bbase[b + 1];
    for (int i = e0 + t; i < e1; i += PB)
        atomicAdd(&hist[pairs[i] >> 17], 1);
    __syncthreads();
    // inclusive scan of hist[0..511] (double-buffered Hillis-Steele)
    int cb = 0;
    buf[0][t] = hist[t];
    __syncthreads();
    for (int off = 1; off < PB; off <<= 1) {
        int v = buf[cb][t];
        if (t >= off) v += buf[cb][t - off];
        buf[cb ^ 1][t] = v;
        cb ^= 1;
        __syncthreads();
    }
    int excl = buf[cb][t] - hist[t];
    cur[t] = e0 + excl;
    nodeptr[b * GSZ + t] = e0 + excl;             // nodeptr[n] exact: (n>>9)*512+(n&511)=n
    if (b == NB - 1 && t == 0) nodeptr[NB * GSZ] = e1;
    __syncthreads();
    for (int i = e0 + t; i < e1; i += PB) {
        int p = pairs[i];
        int pos = atomicAdd(&cur[p >> 17], 1);
        srcs[pos] = p & 0x1FFFF;                  // bucket-local 4B writes
    }
}

#define ACC16(P) { float4 q0 = (P)[0], q1 = (P)[1], q2 = (P)[2], q3 = (P)[3]; \
    acc[0] += q0.x;  acc[1] += q0.y;  acc[2]  += q0.z;  acc[3]  += q0.w;      \
    acc[4] += q1.x;  acc[5] += q1.y;  acc[6]  += q1.z;  acc[7]  += q1.w;      \
    acc[8] += q2.x;  acc[9] += q2.y;  acc[10] += q2.z;  acc[11] += q2.w;      \
    acc[12] += q3.x; acc[13] += q3.y; acc[14] += q3.z;  acc[15] += q3.w; }

// ---- layer 1: per-node register gather-sum (NO atomics) + MLP1 + W2a ----
// 64-thread blocks: wave-granular load balance (1563 blocks over 256 CUs)
__global__ __launch_bounds__(64, 4) void gin1_k(
    const float* __restrict__ xw1, const int* __restrict__ nodeptr,
    const int* __restrict__ srcs, const float* __restrict__ b1a,
    const float* __restrict__ W1b, const float* __restrict__ b1b,
    const float* __restrict__ W2a, float* __restrict__ h1w) {
    __shared__ float sW1b[F1 * F1];
    __shared__ float sW2a[F1 * F2];
    __shared__ float sb1a[F1];
    __shared__ float sb1b[F1];
    int t = threadIdx.x;
    for (int i = t; i < F1 * F1; i += 64) sW1b[i] = W1b[i];
    for (int i = t; i < F1 * F2; i += 64) sW2a[i] = W2a[i];
    if (t < F1) { sb1a[t] = b1a[t]; sb1b[t] = b1b[t]; }
    __syncthreads();

    int n = blockIdx.x * 64 + t;
    if (n >= N_NODES) return;

    float acc[F1];
#pragma unroll
    for (int k = 0; k < F1; k++) acc[k] = 0.0f;

    const float4* X = reinterpret_cast<const float4*>(xw1);
    int e = nodeptr[n];
    int end = nodeptr[n + 1];
    for (; e + 8 <= end; e += 8) {       // deep unroll: 8 rows in flight
        const float4* p0 = X + srcs[e + 0] * 4;
        const float4* p1 = X + srcs[e + 1] * 4;
        const float4* p2 = X + srcs[e + 2] * 4;
        const float4* p3 = X + srcs[e + 3] * 4;
        const float4* p4 = X + srcs[e + 4] * 4;
        const float4* p5 = X + srcs[e + 5] * 4;
        const float4* p6 = X + srcs[e + 6] * 4;
        const float4* p7 = X + srcs[e + 7] * 4;
        ACC16(p0); ACC16(p1); ACC16(p2); ACC16(p3);
        ACC16(p4); ACC16(p5); ACC16(p6); ACC16(p7);
    }
    if (e + 4 <= end) {
        const float4* p0 = X + srcs[e + 0] * 4;
        const float4* p1 = X + srcs[e + 1] * 4;
        const float4* p2 = X + srcs[e + 2] * 4;
        const float4* p3 = X + srcs[e + 3] * 4;
        ACC16(p0); ACC16(p1); ACC16(p2); ACC16(p3);
        e += 4;
    }
    for (; e < end; e++) {
        const float4* p0 = X + srcs[e] * 4;
        ACC16(p0);
    }
    {   // self term
        const float4* pn = X + n * 4;
        ACC16(pn);
    }

    float u[F1];
#pragma unroll
    for (int k = 0; k < F1; k++) u[k] = fmaxf(acc[k] + sb1a[k], 0.0f);
    float h[F1];
#pragma unroll
    for (int j = 0; j < F1; j++) {
        float s = sb1b[j];
#pragma unroll
        for (int k = 0; k < F1; k++) s += u[k] * sW1b[k * F1 + j];
        h[j] = fmaxf(s, 0.0f);          // relu∘relu = relu
    }
    float o[F2];
#pragma unroll
    for (int j = 0; j < F2; j++) {
        float s = 0.0f;
#pragma unroll
        for (int k = 0; k < F1; k++) s += h[k] * sW2a[k * F2 + j];
        o[j] = s;
    }
    float4* hp = reinterpret_cast<float4*>(h1w) + n * 2;
    hp[0] = make_float4(o[0], o[1], o[2], o[3]);
    hp[1] = make_float4(o[4], o[5], o[6], o[7]);
}

#define ACC8(P) { float4 q0 = (P)[0], q1 = (P)[1];                        \
    acc[0] += q0.x; acc[1] += q0.y; acc[2] += q0.z; acc[3] += q0.w;       \
    acc[4] += q1.x; acc[5] += q1.y; acc[6] += q1.z; acc[7] += q1.w; }

// ---- layer 2: per-node register gather-sum + MLP2 + fused mean-pool ----
__global__ __launch_bounds__(64, 4) void gin2pool_k(
    const float* __restrict__ h1w, const int* __restrict__ nodeptr,
    const int* __restrict__ srcs, const float* __restrict__ b2a,
    const float* __restrict__ W2b, const float* __restrict__ b2b,
    const int* __restrict__ batch, float* __restrict__ gsum,
    float* __restrict__ gcnt) {
    __shared__ float sW2b[F2 * F2];
    __shared__ float sb2a[F2];
    __shared__ float sb2b[F2];
    __shared__ float ls[NGRAPH * F2];   // strided loops: 512 > blockDim
    __shared__ float lc[NGRAPH];
    int t = threadIdx.x;
    for (int i = t; i < F2 * F2; i += 64) sW2b[i] = W2b[i];
    if (t < F2) { sb2a[t] = b2a[t]; sb2b[t] = b2b[t]; }
    for (int i = t; i < NGRAPH * F2; i += 64) ls[i] = 0.0f;
    for (int i = t; i < NGRAPH; i += 64) lc[i] = 0.0f;
    __syncthreads();

    int n = blockIdx.x * 64 + t;
    if (n < N_NODES) {
        float acc[F2];
#pragma unroll
        for (int k = 0; k < F2; k++) acc[k] = 0.0f;

        const float4* H = reinterpret_cast<const float4*>(h1w);
        int e = nodeptr[n];
        int end = nodeptr[n + 1];
        for (; e + 8 <= end; e += 8) {
            const float4* p0 = H + srcs[e + 0] * 2;
            const float4* p1 = H + srcs[e + 1] * 2;
            const float4* p2 = H + srcs[e + 2] * 2;
            const float4* p3 = H + srcs[e + 3] * 2;
            const float4* p4 = H + srcs[e + 4] * 2;
            const float4* p5 = H + srcs[e + 5] * 2;
            const float4* p6 = H + srcs[e + 6] * 2;
            const float4* p7 = H + srcs[e + 7] * 2;
            ACC8(p0); ACC8(p1); ACC8(p2); ACC8(p3);
            ACC8(p4); ACC8(p5); ACC8(p6); ACC8(p7);
        }
        if (e + 4 <= end) {
            const float4* p0 = H + srcs[e + 0] * 2;
            const float4* p1 = H + srcs[e + 1] * 2;
            const float4* p2 = H + srcs[e + 2] * 2;
            const float4* p3 = H + srcs[e + 3] * 2;
            ACC8(p0); ACC8(p1); ACC8(p2); ACC8(p3);
            e += 4;
        }
        for (; e < end; e++) {
            const float4* p0 = H + srcs[e] * 2;
            ACC8(p0);
        }
        {   // self term
            const float4* pn = H + n * 2;
            ACC8(pn);
        }

        float u[F2];
#pragma unroll
        for (int k = 0; k < F2; k++)
            u[k] = fmaxf(acc[k] + sb2a[k], 0.0f);
        float v[F2];
#pragma unroll
        for (int j = 0; j < F2; j++) {
            float s = sb2b[j];
#pragma unroll
            for (int k = 0; k < F2; k++) s += u[k] * sW2b[k * F2 + j];
            v[j] = fmaxf(s, 0.0f);
        }
        int g = batch[n];
#pragma unroll
        for (int j = 0; j < F2; j++) atomicAdd(&ls[g * F2 + j], v[j]);
        atomicAdd(&lc[g], 1.0f);
    }
    __syncthreads();
    // sorted batch => a 64-node block spans <=2 graphs => flush is sparse
    for (int i = t; i < NGRAPH * F2; i += 64)
        if (ls[i] != 0.0f) atomicAdd(&gsum[i], ls[i]);
    for (int i = t; i < NGRAPH; i += 64)
        if (lc[i] != 0.0f) atomicAdd(&gcnt[i], lc[i]);
}

// ---------------- final: pooled -> FC -> log_softmax ----------------
__global__ void final_k(const float* __restrict__ gsum,
                        const float* __restrict__ gcnt,
                        const float* __restrict__ Wfc, const float* __restrict__ bfc,
                        float* __restrict__ out) {
    int g = threadIdx.x;
    if (g >= NGRAPH) return;
    float cnt = fmaxf(gcnt[g], 1.0f);
    float p[F2];
#pragma unroll
    for (int f = 0; f < F2; f++) p[f] = gsum[g * F2 + f] / cnt;
    float l[NCLS];
#pragma unroll
    for (int c = 0; c < NCLS; c++) {
        float s = bfc[c];
#pragma unroll
        for (int f = 0; f < F2; f++) s += p[f] * Wfc[f * NCLS + c];
        l[c] = s;
    }
    float m = -INFINITY;
#pragma unroll
    for (int c = 0; c < NCLS; c++) m = fmaxf(m, l[c]);
    float s = 0.0f;
#pragma unroll
    for (int c = 0; c < NCLS; c++) s += expf(l[c] - m);
    float lse = m + logf(s);
#pragma unroll
    for (int c = 0; c < NCLS; c++) out[g * NCLS + c] = l[c] - lse;
}

extern "C" void kernel_launch(void* const* d_in, const int* in_sizes, int n_in,
                              void* d_out, int out_size, void* d_ws, size_t ws_size,
                              hipStream_t stream) {
    const float* x    = (const float*)d_in[0];
    const int*   ei   = (const int*)d_in[1];   // [2, N_EDGES]
    const int*   batch= (const int*)d_in[2];   // [N_NODES], sorted
    const float* W1a  = (const float*)d_in[3];
    const float* b1a  = (const float*)d_in[4];
    const float* W1b  = (const float*)d_in[5];
    const float* b1b  = (const float*)d_in[6];
    const float* W2a  = (const float*)d_in[7];
    const float* b2a  = (const float*)d_in[8];
    const float* W2b  = (const float*)d_in[9];
    const float* b2b  = (const float*)d_in[10];
    const float* Wfc  = (const float*)d_in[11];
    const float* bfc  = (const float*)d_in[12];
    float* out = (float*)d_out;

    // workspace layout (4-byte units), ~22.9 MB total
    float* ws      = (float*)d_ws;
    float* xw1     = ws;                                   // N_NODES*16 (16B aligned)
    float* h1w     = xw1 + (size_t)N_NODES * F1;           // N_NODES*8
    int*   pairs   = (int*)(h1w + (size_t)N_NODES * F2);   // N_EDGES
    int*   srcs    = pairs + N_EDGES;                      // N_EDGES (dst-sorted)
    int*   nodeptr = srcs + N_EDGES;                       // NB*GSZ+1 = 100353
    int*   bbase   = nodeptr + NB * GSZ + 4;               // 257
    int*   gcursor = bbase + 260;                          // 256
    int*   bhist   = gcursor + 256;                        // 256     (memset)
    float* gsum    = (float*)(bhist + 256);                // NGRAPH*F2 (memset)
    float* gcnt   = gsum + NGRAPH * F2;                    // NGRAPH  (memset)

    // one tiny memset: bhist + gsum + gcnt adjacent
    hipMemsetAsync(bhist, 0, (256 + NGRAPH * F2 + NGRAPH) * sizeof(int), stream);

    xform_k<<<NBX, 256, 0, stream>>>(x, W1a, xw1, ei, bhist);
    bscan_k<<<1, 256, 0, stream>>>(bhist, bbase, gcursor);
    passA_k<<<NCH, 256, 0, stream>>>(ei, gcursor, pairs);
    passB_k<<<NB, PB, 0, stream>>>(pairs, bbase, srcs, nodeptr);
    gin1_k<<<(N_NODES + 63) / 64, 64, 0, stream>>>(xw1, nodeptr, srcs,
                                                   b1a, W1b, b1b, W2a, h1w);
    gin2pool_k<<<(N_NODES + 63) / 64, 64, 0, stream>>>(h1w, nodeptr, srcs,
                                                       b2a, W2b, b2b, batch,
                                                       gsum, gcnt);
    final_k<<<1, 64, 0, stream>>>(gsum, gcnt, Wfc, bfc, out);
}